// Round 2
// baseline (454.015 us; speedup 1.0000x reference)
//
#include <hip/hip_runtime.h>

// out[b, j] = x[b, j] * fabsf(W[j, j]),  B=65536, D=1024, all fp32.
// Pure streaming: 268 MB read + 268 MB write. Roofline ~85 us @ 6.4 TB/s.
//
// NOTE: harness passes out_size in ELEMENTS (floats), not bytes.
//       n4 = out_size / 4 = 16,777,216 float4s.
//
// vs previous (441 us) version:
//  - LDS staging removed: stride (GRID*BLOCK = 2,097,152) is a multiple of
//    D4=256, so thread t always handles float4-column t -> its 4 diagonal
//    scales are loop-invariant registers. (ds[t] was written and read only
//    by thread t: the LDS round-trip + per-iter ds_read was pure overhead.)
//  - Fully unrolled 8-iteration fast path: all 8 independent
//    global_load_dwordx4 issued before any store (max read MLP).
//  - Non-temporal load/store hints: zero-reuse streams, skip cache retention.

typedef float f32x4 __attribute__((ext_vector_type(4)));

#define D      1024
#define D4     (D / 4)       // 256 float4 columns
#define BLOCK  256
#define GRID   8192          // 2M threads; 16,777,216 float4s / 2,097,152 = 8 iters
#define UNROLL 8

__global__ __launch_bounds__(BLOCK) void diag_scale_kernel(
    const f32x4* __restrict__ x4,
    const float* __restrict__ W,
    f32x4*       __restrict__ out4,
    long long n4) {
  const int t = threadIdx.x;

  // Loop-invariant diagonal scales for this thread's column group (4*t..4*t+3).
  // W[j, j] = W[j * (D+1)] in row-major [D, D].
  const int j = 4 * t;
  f32x4 dv;
  dv.x = fabsf(W[(long long)(j + 0) * (D + 1)]);
  dv.y = fabsf(W[(long long)(j + 1) * (D + 1)]);
  dv.z = fabsf(W[(long long)(j + 2) * (D + 1)]);
  dv.w = fabsf(W[(long long)(j + 3) * (D + 1)]);

  const long long stride = (long long)GRID * BLOCK;            // 2,097,152
  const long long base   = (long long)blockIdx.x * BLOCK + t;

  if (n4 == (long long)UNROLL * stride) {
    // Fast path: exactly 8 float4s per thread, known at compile time.
    f32x4 v[UNROLL];
#pragma unroll
    for (int k = 0; k < UNROLL; ++k) {
      v[k] = __builtin_nontemporal_load(x4 + base + (long long)k * stride);
    }
#pragma unroll
    for (int k = 0; k < UNROLL; ++k) {
      v[k] *= dv;
      __builtin_nontemporal_store(v[k], out4 + base + (long long)k * stride);
    }
  } else {
    // General grid-stride fallback (correct for any n4).
    for (long long i = base; i < n4; i += stride) {
      f32x4 xv = __builtin_nontemporal_load(x4 + i);
      xv *= dv;
      __builtin_nontemporal_store(xv, out4 + i);
    }
  }
}

extern "C" void kernel_launch(void* const* d_in, const int* in_sizes, int n_in,
                              void* d_out, int out_size, void* d_ws, size_t ws_size,
                              hipStream_t stream) {
  const float* x = (const float*)d_in[0];
  const float* W = (const float*)d_in[1];
  float* out = (float*)d_out;

  // out_size is in ELEMENTS (floats): 65536*1024 = 67,108,864 -> 16,777,216 float4s.
  const long long n4 = (long long)out_size / 4;

  diag_scale_kernel<<<GRID, BLOCK, 0, stream>>>(
      (const f32x4*)x, W, (f32x4*)out, n4);
}

// Round 3
// 442.191 us; speedup vs baseline: 1.0267x; 1.0267x over previous
//
#include <hip/hip_runtime.h>

// out[b, j] = x[b, j] * fabsf(W[j, j]),  B=65536, D=1024, all fp32.
// Pure streaming: 268 MB read + 268 MB write. Roofline ~85-95 us @ ~6 TB/s mixed.
//
// NOTE: harness passes out_size in ELEMENTS (floats), not bytes.
//       n4 = out_size / 4 = 16,777,216 float4s.
//
// Round 3: revert non-temporal hints (R2: 454 us vs 441 baseline; nt loads
// forfeit L3 residency of x (exactly 256 MiB = L3 size) and nt stores skip
// L2 write combining). Keep the R2 wins:
//  - LDS staging removed: stride (GRID*BLOCK = 2,097,152) is a multiple of
//    D4=256, so thread t always handles float4-column t -> its 4 diagonal
//    scales are loop-invariant registers.
//  - Fully unrolled 8-iteration fast path: all 8 independent
//    global_load_dwordx4 issued before any store (max read MLP).

typedef float f32x4 __attribute__((ext_vector_type(4)));

#define D      1024
#define D4     (D / 4)       // 256 float4 columns
#define BLOCK  256
#define GRID   8192          // 2M threads; 16,777,216 float4s / 2,097,152 = 8 iters
#define UNROLL 8

__global__ __launch_bounds__(BLOCK) void diag_scale_kernel(
    const f32x4* __restrict__ x4,
    const float* __restrict__ W,
    f32x4*       __restrict__ out4,
    long long n4) {
  const int t = threadIdx.x;

  // Loop-invariant diagonal scales for this thread's column group (4*t..4*t+3).
  // W[j, j] = W[j * (D+1)] in row-major [D, D].
  const int j = 4 * t;
  f32x4 dv;
  dv.x = fabsf(W[(long long)(j + 0) * (D + 1)]);
  dv.y = fabsf(W[(long long)(j + 1) * (D + 1)]);
  dv.z = fabsf(W[(long long)(j + 2) * (D + 1)]);
  dv.w = fabsf(W[(long long)(j + 3) * (D + 1)]);

  const long long stride = (long long)GRID * BLOCK;            // 2,097,152
  const long long base   = (long long)blockIdx.x * BLOCK + t;

  if (n4 == (long long)UNROLL * stride) {
    // Fast path: exactly 8 float4s per thread, known at compile time.
    f32x4 v[UNROLL];
#pragma unroll
    for (int k = 0; k < UNROLL; ++k) {
      v[k] = x4[base + (long long)k * stride];
    }
#pragma unroll
    for (int k = 0; k < UNROLL; ++k) {
      v[k] *= dv;
      out4[base + (long long)k * stride] = v[k];
    }
  } else {
    // General grid-stride fallback (correct for any n4).
    for (long long i = base; i < n4; i += stride) {
      f32x4 xv = x4[i];
      xv *= dv;
      out4[i] = xv;
    }
  }
}

extern "C" void kernel_launch(void* const* d_in, const int* in_sizes, int n_in,
                              void* d_out, int out_size, void* d_ws, size_t ws_size,
                              hipStream_t stream) {
  const float* x = (const float*)d_in[0];
  const float* W = (const float*)d_in[1];
  float* out = (float*)d_out;

  // out_size is in ELEMENTS (floats): 65536*1024 = 67,108,864 -> 16,777,216 float4s.
  const long long n4 = (long long)out_size / 4;

  diag_scale_kernel<<<GRID, BLOCK, 0, stream>>>(
      (const f32x4*)x, W, (f32x4*)out, n4);
}